// Round 6
// baseline (344.889 us; speedup 1.0000x reference)
//
#include <hip/hip_runtime.h>
#include <math.h>
#include <stdint.h>

#define B_ 2
#define T_ 1024
#define S_ 1024
#define E_ 1024
#define H_ 16
#define SCALING_ 0.125f

typedef short bf16x8 __attribute__((ext_vector_type(8)));
typedef float f32x4 __attribute__((ext_vector_type(4)));
typedef unsigned short us8 __attribute__((ext_vector_type(8)));
typedef unsigned short ush;

__device__ __forceinline__ ush f2bf(float x) {  // RNE fp32->bf16
    unsigned int u = __float_as_uint(x);
    return (ush)((u + 0x7fffu + ((u >> 16) & 1u)) >> 16);
}
__device__ __forceinline__ float bf2f(ush h) {
    return __uint_as_float(((unsigned int)h) << 16);
}
__device__ __forceinline__ void split_bf(float x, ush& hh, ush& ll) {
    hh = f2bf(x);
    ll = f2bf(x - bf2f(hh));
}
__device__ __forceinline__ void gl_lds16(const void* g, void* l) {
    __builtin_amdgcn_global_load_lds(
        (const __attribute__((address_space(1))) unsigned int*)g,
        (__attribute__((address_space(3))) unsigned int*)l, 16, 0, 0);
}
template <int CTRL>
__device__ __forceinline__ float dpp_ror(float x) {
    int v = __builtin_amdgcn_update_dpp(0, __float_as_int(x), CTRL, 0xf, 0xf, true);
    return __int_as_float(v);
}
#define FENCE() asm volatile("" ::: "memory")
#define BARRIER() do { FENCE(); __builtin_amdgcn_s_barrier(); FENCE(); } while (0)

// ---------------------------------------------------------------------------
// Mask dtype detection + normalization (validated rounds 1-5).
// ---------------------------------------------------------------------------
__global__ void mask_detect_kernel(const unsigned int* __restrict__ p,
                                   int* __restrict__ mode_out) {
    __shared__ int gt1_s, oddnz_s;
    if (threadIdx.x == 0) { gt1_s = 0; oddnz_s = 0; }
    __syncthreads();
    int gt1 = 0;
    for (int i = threadIdx.x; i < 512; i += 256)
        if (p[i] > 1u) gt1 = 1;
    if (gt1) atomicOr(&gt1_s, 1);
    __syncthreads();
    if (gt1_s == 0) {
        int oddnz = 0;
        for (int i = threadIdx.x; i < 2048; i += 256)
            if ((i & 1) && p[i] != 0u) oddnz = 1;
        if (oddnz) atomicOr(&oddnz_s, 1);
    }
    __syncthreads();
    if (threadIdx.x == 0)
        *mode_out = gt1_s ? 1 : (oddnz_s ? 0 : 2);
}

__global__ void mask_norm_kernel(const void* __restrict__ p,
                                 const int* __restrict__ mode_p,
                                 int* __restrict__ mout) {
    int i = blockIdx.x * 256 + threadIdx.x;
    int mode = *mode_p;
    int v;
    if (mode == 1)      v = (int)((const unsigned char*)p)[i];
    else if (mode == 2) v = ((const int*)p)[2 * i];
    else                v = ((const int*)p)[i];
    mout[i] = v;
}

// ---------------------------------------------------------------------------
// fp32 -> (bf16 hi, bf16 lo) planar split: 4 weights + 3 activations.
// ---------------------------------------------------------------------------
__global__ __launch_bounds__(256) void conv_split7_kernel(
    const float* __restrict__ Wq, const float* __restrict__ Wk,
    const float* __restrict__ Wv, const float* __restrict__ Wo,
    const float* __restrict__ xq, const float* __restrict__ xk,
    const float* __restrict__ xv,
    ush* __restrict__ Wqh, ush* __restrict__ Wql,
    ush* __restrict__ Wkh, ush* __restrict__ Wkl,
    ush* __restrict__ Wvh, ush* __restrict__ Wvl,
    ush* __restrict__ Woh, ush* __restrict__ Wol,
    ush* __restrict__ xqh, ush* __restrict__ xql,
    ush* __restrict__ xkh, ush* __restrict__ xkl,
    ush* __restrict__ xvh, ush* __restrict__ xvl) {
    int bid = blockIdx.x;
    const float* src; ush* dh; ush* dl; int lb;
    if (bid < 2048) {
        int w = bid >> 9; lb = bid & 511;
        if (w == 0)      { src = Wq; dh = Wqh; dl = Wql; }
        else if (w == 1) { src = Wk; dh = Wkh; dl = Wkl; }
        else if (w == 2) { src = Wv; dh = Wvh; dl = Wvl; }
        else             { src = Wo; dh = Woh; dl = Wol; }
    } else {
        int a = (bid - 2048) >> 10; lb = (bid - 2048) & 1023;
        if (a == 0)      { src = xq; dh = xqh; dl = xql; }
        else if (a == 1) { src = xk; dh = xkh; dl = xkl; }
        else             { src = xv; dh = xvh; dl = xvl; }
    }
    int i = (lb * 256 + threadIdx.x) * 8;
    float4 a4 = *(const float4*)&src[i];
    float4 b4 = *(const float4*)&src[i + 4];
    float v[8] = {a4.x, a4.y, a4.z, a4.w, b4.x, b4.y, b4.z, b4.w};
    us8 vh, vl;
#pragma unroll
    for (int j = 0; j < 8; j++) {
        ush hh, ll;
        split_bf(v[j], hh, ll);
        vh[j] = hh; vl[j] = ll;
    }
    *(us8*)&dh[i] = vh;
    *(us8*)&dl[i] = vl;
}

// ---------------------------------------------------------------------------
// Split-bf16 GEMM, 3-buffer counted-vmcnt pipeline.
// Tile 64x64, 4 waves (2m x 2n), each wave 32x32 out. BK=32, 16x16x32 MFMA,
// 3-term split. LDS: 3 bufs x 16KB = 48KB (3 blocks/CU).
// Stage = 4 gl_lds/thread; steady outstanding 8; wait vmcnt(4) -> stage(t)
// landed while stage(t+1) stays in flight across the barrier (T4).
// Chunk swizzle (row of 64B = 4x16B): chunk' = chunk ^ ((row>>1)&3).
// ---------------------------------------------------------------------------
template <int N, int K, int ROWBIAS, int SPLITOUT>
__device__ __forceinline__ void gemm_body3(
    int bid,
    const ush* __restrict__ Ahg, const ush* __restrict__ Alg,
    const ush* __restrict__ Bhg, const ush* __restrict__ Blg,
    const float* __restrict__ bias,
    ush* __restrict__ outh, ush* __restrict__ outl,
    float* __restrict__ outf, float alpha, ush* lds) {
    const int tid = threadIdx.x;
    const int lane = tid & 63;
    const int wave = tid >> 6;
    const int wm = wave >> 1, wn = wave & 1;
    const int bn = bid % (N / 64);
    const int bm = bid / (N / 64);
    const int m0 = bm * 64, n0 = bn * 64;
    constexpr int NT = K / 32;
    const int row = tid >> 2, oct = tid & 3;
    const int oct2 = oct ^ ((row >> 1) & 3);

    f32x4 acc[2][2];
#pragma unroll
    for (int i = 0; i < 2; i++)
#pragma unroll
        for (int j = 0; j < 2; j++) acc[i][j] = (f32x4){0.f, 0.f, 0.f, 0.f};

    auto stage = [&](int k0, ush* buf) {
        size_t ga = (size_t)(m0 + row) * K + k0 + oct2 * 8;
        gl_lds16(&Ahg[ga], &buf[tid * 8]);
        gl_lds16(&Alg[ga], &buf[2048 + tid * 8]);
        size_t gb = (size_t)(n0 + row) * K + k0 + oct2 * 8;
        gl_lds16(&Bhg[gb], &buf[4096 + tid * 8]);
        gl_lds16(&Blg[gb], &buf[6144 + tid * 8]);
    };

    ush* p0 = lds;
    ush* p1 = lds + 8192;
    ush* p2 = lds + 16384;
    stage(0, p0);
    stage(32, p1);

    for (int t = 0; t < NT; t++) {
        if (t + 1 < NT) asm volatile("s_waitcnt vmcnt(4)" ::: "memory");
        else            asm volatile("s_waitcnt vmcnt(0)" ::: "memory");
        BARRIER();
        if (t + 2 < NT) stage((t + 2) * 32, p2);

        bf16x8 afr[2][2], bfr[2][2];
#pragma unroll
        for (int nj = 0; nj < 2; nj++) {
            int rowB = wn * 32 + nj * 16 + (lane & 15);
            int ch = (lane >> 4) ^ ((rowB >> 1) & 3);
            bfr[nj][0] = *(const bf16x8*)&p0[4096 + rowB * 32 + ch * 8];
            bfr[nj][1] = *(const bf16x8*)&p0[6144 + rowB * 32 + ch * 8];
        }
#pragma unroll
        for (int mi = 0; mi < 2; mi++) {
            int rowA = wm * 32 + mi * 16 + (lane & 15);
            int ch = (lane >> 4) ^ ((rowA >> 1) & 3);
            afr[mi][0] = *(const bf16x8*)&p0[rowA * 32 + ch * 8];
            afr[mi][1] = *(const bf16x8*)&p0[2048 + rowA * 32 + ch * 8];
        }
        __builtin_amdgcn_s_setprio(1);
#pragma unroll
        for (int mi = 0; mi < 2; mi++)
#pragma unroll
            for (int nj = 0; nj < 2; nj++) {
                acc[mi][nj] = __builtin_amdgcn_mfma_f32_16x16x32_bf16(afr[mi][0], bfr[nj][0], acc[mi][nj], 0, 0, 0);
                acc[mi][nj] = __builtin_amdgcn_mfma_f32_16x16x32_bf16(afr[mi][1], bfr[nj][0], acc[mi][nj], 0, 0, 0);
                acc[mi][nj] = __builtin_amdgcn_mfma_f32_16x16x32_bf16(afr[mi][0], bfr[nj][1], acc[mi][nj], 0, 0, 0);
            }
        __builtin_amdgcn_s_setprio(0);

        ush* tmp = p0; p0 = p1; p1 = p2; p2 = tmp;
    }

    float bcol[2];
    if (!ROWBIAS) {
#pragma unroll
        for (int nj = 0; nj < 2; nj++)
            bcol[nj] = bias[n0 + wn * 32 + nj * 16 + (lane & 15)];
    }
#pragma unroll
    for (int mi = 0; mi < 2; mi++) {
#pragma unroll
        for (int r = 0; r < 4; r++) {
            int orow = m0 + wm * 32 + mi * 16 + (lane >> 4) * 4 + r;
            float brow = ROWBIAS ? bias[orow] : 0.f;
#pragma unroll
            for (int nj = 0; nj < 2; nj++) {
                int col = n0 + wn * 32 + nj * 16 + (lane & 15);
                float v = alpha * (acc[mi][nj][r] + (ROWBIAS ? brow : bcol[nj]));
                if (SPLITOUT) {
                    ush hh, ll;
                    split_bf(v, hh, ll);
                    outh[(size_t)orow * N + col] = hh;
                    outl[(size_t)orow * N + col] = ll;
                } else {
                    outf[(size_t)orow * N + col] = v;
                }
            }
        }
    }
}

// Fused Q/K/V projections: 1536 blocks x 256 threads.
__global__ __launch_bounds__(256) void proj_fused_kernel(
    const ush* __restrict__ xqh, const ush* __restrict__ xql,
    const ush* __restrict__ xkh, const ush* __restrict__ xkl,
    const ush* __restrict__ xvh, const ush* __restrict__ xvl,
    const ush* __restrict__ Wqh, const ush* __restrict__ Wql,
    const ush* __restrict__ Wkh, const ush* __restrict__ Wkl,
    const ush* __restrict__ Wvh, const ush* __restrict__ Wvl,
    const float* __restrict__ bq, const float* __restrict__ bk,
    const float* __restrict__ bv_,
    ush* __restrict__ qh, ush* __restrict__ ql,
    ush* __restrict__ kh, ush* __restrict__ kl,
    ush* __restrict__ vth, ush* __restrict__ vtl) {
    __shared__ __align__(16) ush lds[3 * 8192];
    int op = blockIdx.x / 512;
    int bid = blockIdx.x % 512;
    if (op == 0)
        gemm_body3<1024, 1024, 0, 1>(bid, xqh, xql, Wqh, Wql, bq,
                                     qh, ql, nullptr, SCALING_, lds);
    else if (op == 1)
        gemm_body3<1024, 1024, 0, 1>(bid, xkh, xkl, Wkh, Wkl, bk,
                                     kh, kl, nullptr, 1.f, lds);
    else  // v^T = Wv . value^T + bv(row)
        gemm_body3<2048, 1024, 1, 1>(bid, Wvh, Wvl, xvh, xvl, bv_,
                                     vth, vtl, nullptr, 1.f, lds);
}

__global__ __launch_bounds__(256) void gemm_out_kernel(
    const ush* __restrict__ oh, const ush* __restrict__ ol,
    const ush* __restrict__ Woh, const ush* __restrict__ Wol,
    const float* __restrict__ bo, float* __restrict__ out) {
    __shared__ __align__(16) ush lds[3 * 8192];
    gemm_body3<1024, 1024, 0, 0>(blockIdx.x, oh, ol, Woh, Wol, bo,
                                 nullptr, nullptr, out, 1.f, lds);
}

// ---------------------------------------------------------------------------
// Flash attention. Block = (b, h, 64 t-rows); 4 waves x 16 t.
// K double-buffered; V single-buffered (restaged after end-of-iter barrier,
// latency hidden under next QK+softmax, counted vmcnt(8) before PV).
// Bias staged via gl_lds into dual 16KB LDS regions; after consumption the
// SAME per-wave 4KB slice is overwritten by that wave's P tile (hi/lo bf16).
// q pre-scaled; V supplied transposed ([E][B*S]).
// K/Q/Vt LDS rows 128B: chunk' = chunk ^ (row&7).
// Bias LDS [64t][64s] f32: 16-float group swizzle col' = col ^ ((t>>2&1)<<4),
// applied via pre-swizzled global source (gl_lds dest stays linear).
// P (per wave [16t][64s] b16): chunk' = chunk ^ f(t), f=((t>>2)&3)<<1|(t&1).
// ---------------------------------------------------------------------------
__global__ __launch_bounds__(256) void flash_kernel(
    const ush* __restrict__ qh, const ush* __restrict__ ql,
    const ush* __restrict__ kh, const ush* __restrict__ kl,
    const ush* __restrict__ vth, const ush* __restrict__ vtl,
    const float* __restrict__ bias, const int* __restrict__ mask,
    ush* __restrict__ oh, ush* __restrict__ ol) {
    __shared__ __align__(16) ush Ksh[2][4096], Ksl[2][4096];  // 32KB
    __shared__ __align__(16) ush Vsh[4096], Vsl[4096];        // 16KB
    __shared__ __align__(16) float BPb[2][4096];              // 32KB bias/P

    const int tid = threadIdx.x;
    const int lane = tid & 63;
    const int wave = tid >> 6;
    const int bh = blockIdx.x >> 4;
    const int tt = blockIdx.x & 15;
    const int b = bh >> 4, h = bh & 15;
    const int t0 = tt * 64;
    const int srow = tid >> 3;
    const int soct = tid & 7;

    // ---- stage Q (into K buffer 0), hoist frags ----
#pragma unroll
    for (int p = 0; p < 2; p++) {
        int row = p * 32 + srow;
        int oc2 = soct ^ (row & 7);
        size_t g = (size_t)(b * T_ + t0 + row) * E_ + h * 64 + oc2 * 8;
        gl_lds16(&qh[g], &Ksh[0][row * 64 + soct * 8]);
        gl_lds16(&ql[g], &Ksl[0][row * 64 + soct * 8]);
    }
    asm volatile("s_waitcnt vmcnt(0)" ::: "memory");
    __syncthreads();
    bf16x8 qfh[2], qfl[2];
    {
        int row = wave * 16 + (lane & 15);
#pragma unroll
        for (int kk = 0; kk < 2; kk++) {
            int ch = (kk * 4 + (lane >> 4)) ^ (row & 7);
            qfh[kk] = *(const bf16x8*)&Ksh[0][row * 64 + ch * 8];
            qfl[kk] = *(const bf16x8*)&Ksl[0][row * 64 + ch * 8];
        }
    }
    __syncthreads();

    float mrow[4] = {-INFINITY, -INFINITY, -INFINITY, -INFINITY};
    float lrow[4] = {0.f, 0.f, 0.f, 0.f};
    f32x4 oacc[4];
#pragma unroll
    for (int dj = 0; dj < 4; dj++) oacc[dj] = (f32x4){0.f, 0.f, 0.f, 0.f};

    auto stage_k = [&](int ti, int c) {
#pragma unroll
        for (int p = 0; p < 2; p++) {
            int row = p * 32 + srow;
            int oc2 = soct ^ (row & 7);
            size_t gk = (size_t)(b * S_ + ti * 64 + row) * E_ + h * 64 + oc2 * 8;
            gl_lds16(&kh[gk], &Ksh[c][row * 64 + soct * 8]);
            gl_lds16(&kl[gk], &Ksl[c][row * 64 + soct * 8]);
        }
    };
    auto stage_v = [&](int ti) {
#pragma unroll
        for (int p = 0; p < 2; p++) {
            int row = p * 32 + srow;
            int oc2 = soct ^ (row & 7);
            size_t gv = (size_t)(h * 64 + row) * (B_ * S_) + b * S_ + ti * 64 + oc2 * 8;
            gl_lds16(&vth[gv], &Vsh[row * 64 + soct * 8]);
            gl_lds16(&vtl[gv], &Vsl[row * 64 + soct * 8]);
        }
    };
    auto stage_bias = [&](int ti, int reg) {
#pragma unroll
        for (int p = 0; p < 4; p++) {
            int row = p * 16 + (tid >> 4);       // 0..63
            int slot = tid & 15;                 // 16B units within 64-col row
            int sslot = slot ^ (((row >> 2) & 1) << 2);
            const float* src = bias + ((size_t)bh * T_ + t0 + row) * S_ +
                               ti * 64 + sslot * 4;
            gl_lds16(src, &BPb[reg][(p * 256 + tid) * 4]);
        }
    };

    // ---- prologue: tile 0 ----
    int mk[4];
    stage_k(0, 0);
    stage_v(0);
    stage_bias(0, 0);
#pragma unroll
    for (int nj = 0; nj < 4; nj++)
        mk[nj] = mask[b * S_ + nj * 16 + (lane & 15)];
    asm volatile("s_waitcnt vmcnt(0)" ::: "memory");
    __syncthreads();

    for (int t = 0; t < 16; t++) {
        const int cur = t & 1;

        // ---- issue next K + bias (stay in flight across the whole iter) ----
        if (t < 15) {
            stage_k(t + 1, cur ^ 1);
            stage_bias(t + 1, cur ^ 1);
        }

        // ---- QK^T (split 3-term) from Kb[cur] ----
        f32x4 sc[4];
#pragma unroll
        for (int nj = 0; nj < 4; nj++) sc[nj] = (f32x4){0.f, 0.f, 0.f, 0.f};
        __builtin_amdgcn_s_setprio(1);
#pragma unroll
        for (int kk = 0; kk < 2; kk++) {
#pragma unroll
            for (int nj = 0; nj < 4; nj++) {
                int row = nj * 16 + (lane & 15);
                int ch = (kk * 4 + (lane >> 4)) ^ (row & 7);
                bf16x8 kfh = *(const bf16x8*)&Ksh[cur][row * 64 + ch * 8];
                bf16x8 kfl = *(const bf16x8*)&Ksl[cur][row * 64 + ch * 8];
                sc[nj] = __builtin_amdgcn_mfma_f32_16x16x32_bf16(qfh[kk], kfh, sc[nj], 0, 0, 0);
                sc[nj] = __builtin_amdgcn_mfma_f32_16x16x32_bf16(qfl[kk], kfh, sc[nj], 0, 0, 0);
                sc[nj] = __builtin_amdgcn_mfma_f32_16x16x32_bf16(qfh[kk], kfl, sc[nj], 0, 0, 0);
            }
        }
        __builtin_amdgcn_s_setprio(0);

        // ---- bias from LDS; mask -> -inf BEFORE bias add ----
        {
            const float* bp = &BPb[cur][wave * 1024];
#pragma unroll
            for (int r = 0; r < 4; r++) {
                int tl = (lane >> 4) * 4 + r;
                int sx = ((tl >> 2) & 1) << 4;
#pragma unroll
                for (int nj = 0; nj < 4; nj++) {
                    int s = (nj * 16 + (lane & 15)) ^ sx;
                    float bvv = bp[tl * 64 + s];
                    float v = mk[nj] ? -INFINITY : sc[nj][r];
                    sc[nj][r] = v + bvv;
                }
            }
        }
        // ---- prefetch next mask ----
        if (t < 15) {
            const int s0n = (t + 1) * 64;
#pragma unroll
            for (int nj = 0; nj < 4; nj++)
                mk[nj] = mask[b * S_ + s0n + nj * 16 + (lane & 15)];
        }

        // ---- online softmax (DPP rotate-reduce over 16-lane groups) ----
        ush phv[4][4], plv[4][4];
#pragma unroll
        for (int r = 0; r < 4; r++) {
            float mx = fmaxf(fmaxf(sc[0][r], sc[1][r]), fmaxf(sc[2][r], sc[3][r]));
            mx = fmaxf(mx, dpp_ror<0x121>(mx));
            mx = fmaxf(mx, dpp_ror<0x122>(mx));
            mx = fmaxf(mx, dpp_ror<0x124>(mx));
            mx = fmaxf(mx, dpp_ror<0x128>(mx));
            float mnew = fmaxf(mrow[r], mx);
            float esc = __expf(mrow[r] - mnew);
            float ps = 0.f;
#pragma unroll
            for (int nj = 0; nj < 4; nj++) {
                float p = __expf(sc[nj][r] - mnew);
                ps += p;
                split_bf(p, phv[nj][r], plv[nj][r]);
            }
            ps += dpp_ror<0x121>(ps);
            ps += dpp_ror<0x122>(ps);
            ps += dpp_ror<0x124>(ps);
            ps += dpp_ror<0x128>(ps);
            lrow[r] = lrow[r] * esc + ps;
            mrow[r] = mnew;
#pragma unroll
            for (int dj = 0; dj < 4; dj++) oacc[dj][r] *= esc;
        }

        // ---- write P over this wave's consumed bias slice ----
        ush* Pw = (ush*)&BPb[cur][wave * 1024];  // [0..1023]=hi, [1024..]=lo
#pragma unroll
        for (int r = 0; r < 4; r++) {
            int tq = (lane >> 4) * 4 + r;
            int f = (((tq >> 2) & 3) << 1) | (tq & 1);
#pragma unroll
            for (int nj = 0; nj < 4; nj++) {
                int s = nj * 16 + (lane & 15);
                int idx = tq * 64 + (((s >> 3) ^ f) * 8) + (s & 7);
                Pw[idx] = phv[nj][r];
                Pw[1024 + idx] = plv[nj][r];
            }
        }
        bf16x8 pah[2], pal[2];
        {
            int tq = lane & 15;
            int f = (((tq >> 2) & 3) << 1) | (tq & 1);
#pragma unroll
            for (int kk = 0; kk < 2; kk++) {
                int ch = (kk * 4 + (lane >> 4)) ^ f;
                pah[kk] = *(const bf16x8*)&Pw[tq * 64 + ch * 8];
                pal[kk] = *(const bf16x8*)&Pw[1024 + tq * 64 + ch * 8];
            }
        }

        // ---- V(t) guaranteed landed (oldest in queue) ----
        if (t < 15) asm volatile("s_waitcnt vmcnt(8)" ::: "memory");
        else        asm volatile("s_waitcnt vmcnt(0)" ::: "memory");

        __builtin_amdgcn_s_setprio(1);
#pragma unroll
        for (int dj = 0; dj < 4; dj++) {
            int row = dj * 16 + (lane & 15);
#pragma unroll
            for (int kk = 0; kk < 2; kk++) {
                int ch = (kk * 4 + (lane >> 4)) ^ (row & 7);
                bf16x8 vfh = *(const bf16x8*)&Vsh[row * 64 + ch * 8];
                bf16x8 vfl = *(const bf16x8*)&Vsl[row * 64 + ch * 8];
                oacc[dj] = __builtin_amdgcn_mfma_f32_16x16x32_bf16(pah[kk], vfh, oacc[dj], 0, 0, 0);
                oacc[dj] = __builtin_amdgcn_mfma_f32_16x16x32_bf16(pal[kk], vfh, oacc[dj], 0, 0, 0);
                oacc[dj] = __builtin_amdgcn_mfma_f32_16x16x32_bf16(pah[kk], vfl, oacc[dj], 0, 0, 0);
            }
        }
        __builtin_amdgcn_s_setprio(0);

        // ---- drain K/bias(t+1) (issued a full iter ago), sync, restage V ----
        asm volatile("s_waitcnt vmcnt(0)" ::: "memory");
        BARRIER();
        if (t < 15) stage_v(t + 1);
    }

    // ---- epilogue: O = acc / l, split-store ----
#pragma unroll
    for (int r = 0; r < 4; r++) {
        float inv = 1.f / lrow[r];
        int t = t0 + wave * 16 + (lane >> 4) * 4 + r;
#pragma unroll
        for (int dj = 0; dj < 4; dj++) {
            float v = oacc[dj][r] * inv;
            ush hh, ll;
            split_bf(v, hh, ll);
            size_t g = (size_t)(b * T_ + t) * E_ + h * 64 + dj * 16 + (lane & 15);
            oh[g] = hh;
            ol[g] = ll;
        }
    }
}

// ---------------------------------------------------------------------------
extern "C" void kernel_launch(void* const* d_in, const int* in_sizes, int n_in,
                              void* d_out, int out_size, void* d_ws,
                              size_t ws_size, hipStream_t stream) {
    const float* query = (const float*)d_in[0];
    const float* key   = (const float*)d_in[1];
    const float* value = (const float*)d_in[2];
    const void*  kpm   = d_in[3];
    const float* attn_bias = (const float*)d_in[4];
    const float* Wq = (const float*)d_in[5];
    const float* bq = (const float*)d_in[6];
    const float* Wk = (const float*)d_in[7];
    const float* bk = (const float*)d_in[8];
    const float* Wv = (const float*)d_in[9];
    const float* bv = (const float*)d_in[10];
    const float* Wo = (const float*)d_in[11];
    const float* bo = (const float*)d_in[12];
    float* out = (float*)d_out;

    char* ws = (char*)d_ws;
    const size_t MB = 1024 * 1024;
    ush* Wqh = (ush*)(ws + 0 * MB);
    ush* Wql = (ush*)(ws + 2 * MB);
    ush* Wkh = (ush*)(ws + 4 * MB);
    ush* Wkl = (ush*)(ws + 6 * MB);
    ush* Wvh = (ush*)(ws + 8 * MB);
    ush* Wvl = (ush*)(ws + 10 * MB);
    ush* Woh = (ush*)(ws + 12 * MB);
    ush* Wol = (ush*)(ws + 14 * MB);
    ush* qh  = (ush*)(ws + 16 * MB);
    ush* ql  = (ush*)(ws + 20 * MB);
    ush* kh  = (ush*)(ws + 24 * MB);
    ush* kl  = (ush*)(ws + 28 * MB);
    ush* vth = (ush*)(ws + 32 * MB);  // V^T [E][B*S]
    ush* vtl = (ush*)(ws + 36 * MB);
    ush* xqh = (ush*)(ws + 40 * MB);
    ush* xql = (ush*)(ws + 44 * MB);
    ush* xkh = (ush*)(ws + 48 * MB);
    ush* xkl = (ush*)(ws + 52 * MB);
    ush* xvh = (ush*)(ws + 56 * MB);
    ush* xvl = (ush*)(ws + 60 * MB);
    ush* oh  = (ush*)(ws + 40 * MB);  // overlays xq planes (dead after proj)
    ush* ol  = (ush*)(ws + 44 * MB);
    int* masknorm = (int*)(ws + 64 * MB);
    int* mode = masknorm + 2048;

    conv_split7_kernel<<<5120, 256, 0, stream>>>(
        Wq, Wk, Wv, Wo, query, key, value,
        Wqh, Wql, Wkh, Wkl, Wvh, Wvl, Woh, Wol,
        xqh, xql, xkh, xkl, xvh, xvl);
    mask_detect_kernel<<<1, 256, 0, stream>>>((const unsigned int*)kpm, mode);
    mask_norm_kernel<<<8, 256, 0, stream>>>(kpm, mode, masknorm);

    proj_fused_kernel<<<1536, 256, 0, stream>>>(
        xqh, xql, xkh, xkl, xvh, xvl,
        Wqh, Wql, Wkh, Wkl, Wvh, Wvl, bq, bk, bv,
        qh, ql, kh, kl, vth, vtl);

    flash_kernel<<<512, 256, 0, stream>>>(qh, ql, kh, kl, vth, vtl, attn_bias,
                                          masknorm, oh, ol);

    gemm_out_kernel<<<512, 256, 0, stream>>>(oh, ol, Woh, Wol, bo, out);
}